// Round 9
// baseline (456.005 us; speedup 1.0000x reference)
//
#include <hip/hip_runtime.h>
#include <hip/hip_bf16.h>
#include <hip/hip_fp16.h>
#include <math.h>

// GuidedUpsampleUnitGF — R9: conv2 K-split (2048 blocks, 5/CU occupancy) with unrelu'd fp16
// partials summed in gf_stream; upsample+guide+prep merged into one launch (7 total).

#define P2 65536            // 256*256 pixels
#define PADW 260            // padded image width/height for conv2 (halo 2)

typedef short  frag8  __attribute__((ext_vector_type(8)));   // 8 bf16 (4 VGPRs)
typedef float  f32x4  __attribute__((ext_vector_type(4)));

__device__ __forceinline__ void load16_lds(const void* gsrc, void* lds) {
    __builtin_amdgcn_global_load_lds((const __attribute__((address_space(1))) void*)gsrc,
                                     (__attribute__((address_space(3))) void*)lds, 16, 0, 0);
}

// bilinear 2x upsample coords (half-pixel centers, edge-clamped {0.25,0.75})
struct BilC { int y0, y1, x0, x1; float wy0, wy1, wx0, wx1; };
__device__ __forceinline__ BilC bil_coords(int oy, int ox) {
    BilC c;
    int m = oy >> 1;
    if ((oy & 1) == 0) { c.y0 = (m > 0) ? m - 1 : 0; c.y1 = m; c.wy0 = 0.25f; }
    else               { c.y0 = m; c.y1 = (m < 127) ? m + 1 : 127; c.wy0 = 0.75f; }
    c.wy1 = 1.0f - c.wy0;
    int n = ox >> 1;
    if ((ox & 1) == 0) { c.x0 = (n > 0) ? n - 1 : 0; c.x1 = n; c.wx0 = 0.25f; }
    else               { c.x0 = n; c.x1 = (n < 127) ? n + 1 : 127; c.wx0 = 0.75f; }
    c.wx1 = 1.0f - c.wx0;
    return c;
}
__device__ __forceinline__ float bil_eval(const float* __restrict__ src, const BilC& c) {
    return c.wy0 * (c.wx0 * src[c.y0 * 128 + c.x0] + c.wx1 * src[c.y0 * 128 + c.x1])
         + c.wy1 * (c.wx0 * src[c.y1 * 128 + c.x0] + c.wx1 * src[c.y1 * 128 + c.x1]);
}

// ---------------------------------------------------------------- merged prep mega-kernel
// b ranges: [0,9216) upsample_x | [9216,9472) guide+stats | [9472,9601) border zero
//           [9601,9665) haccum zero | [9665,10465) w2 repack | [10465,10501) w1 | [10501,10533) w3
__global__ __launch_bounds__(256) void prep_mega(const float* __restrict__ mask,
                                                 const float* __restrict__ fg,
                                                 const float* __restrict__ bg,
                                                 const float* __restrict__ feat,
                                                 const float* __restrict__ w1,
                                                 const float* __restrict__ w2,
                                                 const float* __restrict__ w3,
                                                 __hip_bfloat16* __restrict__ xp,
                                                 float* __restrict__ guide,
                                                 float* __restrict__ meanI,
                                                 float* __restrict__ varI,
                                                 __hip_bfloat16* __restrict__ wpk1,
                                                 __hip_bfloat16* __restrict__ wpk2,
                                                 __hip_bfloat16* __restrict__ wpk3,
                                                 __hip_bfloat16* __restrict__ y1p,
                                                 float* __restrict__ haccum) {
    __shared__ float G[20 * 21];
    int b = blockIdx.x;
    int tid = threadIdx.x;
    if (b < 9216) {                                    // upsample -> xp [36][P2][8]
        int chunk = b >> 8;
        int p = (b & 255) * 256 + tid;
        union { __hip_bfloat16 h[8]; f32x4 v; } u;
        if (chunk >= 33) {
            f32x4 z = {0.f, 0.f, 0.f, 0.f};
            *(f32x4*)&xp[((size_t)chunk * P2 + p) * 8] = z;
            return;
        }
        BilC bc = bil_coords(p >> 8, p & 255);
#pragma unroll
        for (int j = 0; j < 8; j++) {
            int c = chunk * 8 + j;
            float v = 0.f;
            if (c < 263) {
                const float* src = (c == 0) ? mask
                                 : (c < 4)  ? fg + (c - 1) * 16384
                                 : (c < 7)  ? bg + (c - 4) * 16384
                                 :            feat + (c - 7) * 16384;
                v = bil_eval(src, bc);
            }
            u.h[j] = __float2bfloat16(v);
        }
        *(f32x4*)&xp[((size_t)chunk * P2 + p) * 8] = u.v;
    } else if (b < 9472) {                             // fused guide + stats
        int bb = b - 9216;
        int gx0 = (bb & 15) * 16, gy0 = (bb >> 4) * 16;
        for (int i = tid; i < 400; i += 256) {
            int r = i / 20, c = i - r * 20;
            int gy = gy0 + r - 2, gx = gx0 + c - 2;
            float v = 0.f;
            if ((unsigned)gy < 256u && (unsigned)gx < 256u) {
                BilC bc = bil_coords(gy, gx);
                v = (bil_eval(fg, bc) + bil_eval(fg + 16384, bc) + bil_eval(fg + 32768, bc))
                    * (128.0f / 3.0f);
            }
            G[r * 21 + c] = v;
        }
        __syncthreads();
        int ty = tid >> 4, tx = tid & 15;
        int gy = gy0 + ty, gx = gx0 + tx;
        float s = 0.f, ss = 0.f;
#pragma unroll
        for (int dy = 0; dy < 5; dy++)
#pragma unroll
            for (int dx = 0; dx < 5; dx++) {
                float v = G[(ty + dy) * 21 + tx + dx];
                s += v; ss += v * v;
            }
        int cy = ((gy + 2 < 255) ? gy + 2 : 255) - ((gy - 2 > 0) ? gy - 2 : 0) + 1;
        int cx = ((gx + 2 < 255) ? gx + 2 : 255) - ((gx - 2 > 0) ? gx - 2 : 0) + 1;
        float inv = 1.0f / (float)(cy * cx);
        float m = s * inv;
        guide[gy * 256 + gx] = G[(ty + 2) * 21 + tx + 2];
        meanI[gy * 256 + gx] = m;
        varI[gy * 256 + gx]  = ss * inv - m * m;
    } else if (b < 9601) {                             // border zero: 2064 px * 16 chunks
        int idx = (b - 9472) * 256 + tid;
        if (idx >= 33024) return;
        int pid = idx >> 4, chunk = idx & 15;
        int py, px;
        if (pid < 520)       { py = pid / 260;               px = pid - py * 260; }
        else if (pid < 1040) { int t = pid - 520; int r = t / 260; py = 258 + r; px = t - r * 260; }
        else                 { int t = pid - 1040; int r = t >> 2; int c = t & 3;
                               py = 2 + r; px = (c < 2) ? c : 256 + c; }
        f32x4 z = {0.f, 0.f, 0.f, 0.f};
        f32x4* dst = (f32x4*)&y1p[((size_t)py * PADW + px) * 256 + chunk * 16];
        dst[0] = z; dst[1] = z;
    } else if (b < 9665) {                             // haccum zero
        int idx = (b - 9601) * 256 + tid;
        f32x4 z = {0.f, 0.f, 0.f, 0.f};
        *(f32x4*)&haccum[idx * 4] = z;
    } else if (b < 10465) {                            // w2 -> [tap][ict][nb][lane][8]
        int idx = (b - 9665) * 256 + tid;              // 204800
        int lane = idx & 63;
        int nb = (idx >> 6) & 15;
        int kt = (idx >> 10) & 7;
        int t  = idx >> 13;
        int oc = nb * 16 + (lane & 15);
        int ic0 = kt * 32 + (lane >> 4) * 8;
        union { __hip_bfloat16 h[8]; f32x4 v; } u;
#pragma unroll
        for (int j = 0; j < 8; j++)
            u.h[j] = __float2bfloat16(w2[(oc * 256 + ic0 + j) * 25 + t]);
        *(f32x4*)&wpk2[(size_t)idx * 8] = u.v;
    } else {
        const float* W; __hip_bfloat16* dst; int K, KT, idx;
        if (b < 10501) { W = w1; dst = wpk1; K = 263; KT = 9; idx = (b - 10465) * 256 + tid; }
        else           { W = w3; dst = wpk3; K = 256; KT = 8; idx = (b - 10501) * 256 + tid; }
        if (idx >= KT * 16 * 64) return;
        int lane = idx & 63;
        int nbg = (idx >> 6) & 15;
        int kt = idx >> 10;
        int oc = nbg * 16 + (lane & 15);
        int ic0 = kt * 32 + (lane >> 4) * 8;
        union { __hip_bfloat16 h[8]; f32x4 v; } u;
#pragma unroll
        for (int j = 0; j < 8; j++) {
            int ic = ic0 + j;
            u.h[j] = (ic < K) ? __float2bfloat16(W[(size_t)oc * K + ic]) : __float2bfloat16(0.f);
        }
        *(f32x4*)&dst[(size_t)idx * 8] = u.v;
    }
}

// ---------------------------------------------------------------- 1x1 MFMA GEMM, merged oh
// block: 128 px x 256 oc; 4 waves, each 8M x 4N. grid (512).
template<int MODE>
__global__ __launch_bounds__(256) void mfma_1x1(const __hip_bfloat16* __restrict__ xch,
                                                const __hip_bfloat16* __restrict__ wpk,
                                                const float* __restrict__ bias,
                                                void* __restrict__ outp, int KT,
                                                const float* __restrict__ wmv,
                                                float* __restrict__ haccum) {
    __shared__ __align__(16) char smem[MODE == 0 ? 67584 : 49152];
    __hip_bfloat16* Asm0 = (__hip_bfloat16*)smem;                 // [2][128*32]   16 KB
    __hip_bfloat16* Bsm0 = (__hip_bfloat16*)(smem + 16384);       // [2][16*64*8]  32 KB
    const int tid = threadIdx.x;
    const int wave = tid >> 6, lane = tid & 63;
    const int q = lane >> 4, m16 = lane & 15;
    const int wn = wave;
    const int pb = blockIdx.x * 128;

    f32x4 acc[8][4] = {};

    auto stA = [&](int kt, int buf) {
#pragma unroll
        for (int it = 0; it < 2; it++) {
            int chb = it * 256 + wave * 64;
            int ch = chb + lane;
            int px = ch >> 2, oct = ch & 3;
            const __hip_bfloat16* src = xch + ((size_t)(kt * 4 + oct) * P2 + pb + px) * 8;
            load16_lds(src, &Asm0[(size_t)buf * 4096 + chb * 8]);
        }
    };
    auto stB = [&](int kt, int buf) {
#pragma unroll
        for (int it = 0; it < 4; it++) {
            int chb = it * 256 + wave * 64;
            int ch = chb + lane;
            int nb = ch >> 6, l = ch & 63;
            const __hip_bfloat16* src = wpk + (((size_t)kt * 16 + nb) * 64 + l) * 8;
            load16_lds(src, &Bsm0[(size_t)buf * 8192 + chb * 8]);
        }
    };
    stA(0, 0); stB(0, 0);
    int buf = 0;
    for (int kt = 0; kt < KT; kt++) {
        __syncthreads();
        if (kt + 1 < KT) { stA(kt + 1, buf ^ 1); stB(kt + 1, buf ^ 1); }
        frag8 a[8], b[4];
#pragma unroll
        for (int i = 0; i < 8; i++)
            a[i] = *(const frag8*)&Asm0[(size_t)buf * 4096 + (i * 16 + m16) * 32 + q * 8];
#pragma unroll
        for (int j = 0; j < 4; j++)
            b[j] = *(const frag8*)&Bsm0[(size_t)buf * 8192 + ((wn * 4 + j) * 64 + lane) * 8];
#pragma unroll
        for (int i = 0; i < 8; i++)
#pragma unroll
            for (int j = 0; j < 4; j++)
                acc[i][j] = __builtin_amdgcn_mfma_f32_16x16x32_bf16(a[i], b[j], acc[i][j], 0, 0, 0);
        buf ^= 1;
    }
    if (MODE == 0) {
        __syncthreads();
        __hip_bfloat16* Ct = (__hip_bfloat16*)smem;
#pragma unroll
        for (int j = 0; j < 4; j++) {
            int ocr = (wn * 4 + j) * 16 + m16;
            float bj = bias[ocr];
#pragma unroll
            for (int i = 0; i < 8; i++) {
                f32x4 v = acc[i][j];
#pragma unroll
                for (int e = 0; e < 4; e++) {
                    int pxr = i * 16 + q * 4 + e;
                    float tv = v[e] + bj;
                    Ct[pxr * 264 + ocr] = __float2bfloat16(tv > 0.f ? tv : 0.f);
                }
            }
        }
        __syncthreads();
        __hip_bfloat16* y1p = (__hip_bfloat16*)outp;
        int colr = (tid & 31) * 8;
#pragma unroll
        for (int it = 0; it < 16; it++) {
            int pxr = it * 8 + (tid >> 5);
            int pix = pb + pxr;
            int py = pix >> 8, px = pix & 255;
            f32x4 val = *(f32x4*)&Ct[pxr * 264 + colr];
            *(f32x4*)&y1p[((size_t)(py + 2) * PADW + px + 2) * 256 + colr] = val;
        }
    } else {
        float* outf = (float*)outp;
        float hpart[8][4] = {};
#pragma unroll
        for (int j = 0; j < 4; j++) {
            int oc = (wn * 4 + j) * 16 + m16;
            float bj = bias[oc];
            float wj = wmv[oc];
#pragma unroll
            for (int i = 0; i < 8; i++) {
                f32x4 v = acc[i][j];
#pragma unroll
                for (int e = 0; e < 4; e++) {
                    float tv = v[e] + bj;
                    tv = tv > 0.f ? tv : 0.f;
                    v[e] = tv;
                    hpart[i][e] += wj * tv;
                }
                *(f32x4*)&outf[(size_t)oc * P2 + pb + i * 16 + q * 4] = v;
            }
        }
#pragma unroll
        for (int i = 0; i < 8; i++)
#pragma unroll
            for (int e = 0; e < 4; e++) {
                float s = hpart[i][e];
                s += __shfl_xor(s, 1);
                s += __shfl_xor(s, 2);
                s += __shfl_xor(s, 4);
                s += __shfl_xor(s, 8);
                if (m16 == 0)
                    atomicAdd(&haccum[pb + i * 16 + q * 4 + e], s);
            }
    }
}

// ---------------------------------------------------------------- conv2: 5x5 MFMA, R6 core + K-split
// blockIdx.z = oh*2 + khalf. Each block: 4 ic-tiles (100 steps), partial (no relu, bias in kh=0)
// -> fp16 pf[kh*256*P2 + oc*P2 + p]. gf_stream sums+relus.
__global__ __launch_bounds__(128, 2) void conv5x5_mfma(const __hip_bfloat16* __restrict__ y1p,
                                                       const __hip_bfloat16* __restrict__ wpk,
                                                       const float* __restrict__ bias,
                                                       __half* __restrict__ pf) {
    __shared__ __align__(16) __hip_bfloat16 Asm[2][12 * 20 * 32];  // 2 x 15360 B
    const int tid = threadIdx.x;
    const int wave = tid >> 6;
    const int lane = tid & 63;
    const int q = lane >> 4;
    const int m16 = lane & 15;
    const int bx = blockIdx.x, by = blockIdx.y;
    const int oh = blockIdx.z >> 1, kh = blockIdx.z & 1;

    f32x4 acc[4][8] = {};

    auto stageA = [&](int ict, int buf) {              // ict local 0..3
#pragma unroll
        for (int g = 0; g < 8; g++) {
            int grp = g * 2 + wave;
            if (grp >= 15) break;
            int chb = grp * 64;
            int ch = chb + lane;
            int oct = ch & 3, pl = ch >> 2;
            int pc = pl % 20, pr = pl / 20;
            const __hip_bfloat16* src =
                y1p + (size_t)((by * 8 + pr) * PADW + bx * 16 + pc) * 256
                    + (kh * 4 + ict) * 32 + oct * 8;
            load16_lds(src, &Asm[buf][chb * 8]);
        }
    };
    auto loadB = [&](int s, frag8* dst) {
        int ict = s / 25, tap = s - ict * 25;
        const __hip_bfloat16* base =
            wpk + ((size_t)((tap * 8 + kh * 4 + ict) * 16 + oh * 8) * 64 + lane) * 8;
#pragma unroll
        for (int j = 0; j < 8; j++)
            dst[j] = *(const frag8*)(base + (size_t)j * 512);
    };

    frag8 bA[8], bB[8];
    stageA(0, 0);
    loadB(0, bA);
    int abuf = 0;

    auto step = [&](int s, frag8* bcur, frag8* bnxt) {
        int ict = s / 25, tap = s - ict * 25;
        if (tap == 0) __syncthreads();
        if (s + 1 < 100) loadB(s + 1, bnxt);
        if (tap == 24 && ict < 3) stageA(ict + 1, abuf ^ 1);
        int dy = tap / 5, dx = tap - dy * 5;
        frag8 a[4];
#pragma unroll
        for (int i = 0; i < 4; i++)
            a[i] = *(const frag8*)&Asm[abuf][((wave * 4 + i + dy) * 20 + m16 + dx) * 32 + q * 8];
#pragma unroll
        for (int i = 0; i < 4; i++)
#pragma unroll
            for (int j = 0; j < 8; j++)
                acc[i][j] = __builtin_amdgcn_mfma_f32_16x16x32_bf16(a[i], bcur[j], acc[i][j], 0, 0, 0);
        if (tap == 24) abuf ^= 1;
    };
    for (int s = 0; s < 100; s += 2) { step(s, bA, bB); step(s + 1, bB, bA); }

    // epilogue: fp16 partial (no relu), bias only in kh==0
    __half* dst0 = pf + (size_t)kh * 256 * P2;
#pragma unroll
    for (int j = 0; j < 8; j++) {
        int oc = oh * 128 + j * 16 + m16;
        float bj = kh ? 0.f : bias[oc];
#pragma unroll
        for (int i = 0; i < 4; i++) {
            int r = wave * 4 + i;
            f32x4 v = acc[i][j];
            union { __half h[4]; double d; } u;
#pragma unroll
            for (int e = 0; e < 4; e++)
                u.h[e] = __float2half(v[e] + bj);
            *(double*)&dst0[(size_t)oc * P2 + (by * 8 + r) * 256 + bx * 16 + q * 4] = u.d;
        }
    }
}

// ---------------------------------------------------------------- guided filter: streaming separable
// p = relu(p0 + p1) from the two K-split partials
__global__ __launch_bounds__(256) void gf_stream(const __half* __restrict__ pf,
                                                 const float* __restrict__ guide,
                                                 const float* __restrict__ meanI,
                                                 const float* __restrict__ varI,
                                                 __hip_bfloat16* __restrict__ filt) {
    __shared__ float Prow[260], IProw[260], Arow[260], Brow[260];
    const int t = threadIdx.x;
    const int c = blockIdx.y;
    const int Y0 = blockIdx.x * 64;
    const __half* pc0 = pf + (size_t)c * P2;
    const __half* pc1 = pf + (size_t)(256 + c) * P2;
    if (t < 4) {
        int e = (t < 2) ? t : 256 + t;
        Prow[e] = 0.f; IProw[e] = 0.f; Arow[e] = 0.f; Brow[e] = 0.f;
    }
    int xlo = (t - 2 > 0) ? t - 2 : 0, xhi = (t + 2 < 255) ? t + 2 : 255;
    const float cxr = 1.0f / (float)(xhi - xlo + 1);
    float hp[5] = {0, 0, 0, 0, 0}, hip[5] = {0, 0, 0, 0, 0};
    float ha[5] = {0, 0, 0, 0, 0}, hb[5] = {0, 0, 0, 0, 0};
    float vp = 0.f, vip = 0.f, va = 0.f, vb = 0.f;
    __syncthreads();
    for (int s = 0; s < 72; s++) {
        int yL = Y0 - 4 + s;
        bool okL = ((unsigned)yL < 256u);
        if (okL) {
            float pv = __half2float(pc0[yL * 256 + t]) + __half2float(pc1[yL * 256 + t]);
            pv = pv > 0.f ? pv : 0.f;
            Prow[t + 2] = pv;
            IProw[t + 2] = guide[yL * 256 + t] * pv;
        }
        __syncthreads();
        float hpn = 0.f, hipn = 0.f;
        if (okL) {
            hpn  = Prow[t] + Prow[t + 1] + Prow[t + 2] + Prow[t + 3] + Prow[t + 4];
            hipn = IProw[t] + IProw[t + 1] + IProw[t + 2] + IProw[t + 3] + IProw[t + 4];
        }
        vp += hpn - hp[0];  vip += hipn - hip[0];
        hp[0] = hp[1]; hp[1] = hp[2]; hp[2] = hp[3]; hp[3] = hp[4]; hp[4] = hpn;
        hip[0] = hip[1]; hip[1] = hip[2]; hip[2] = hip[3]; hip[3] = hip[4]; hip[4] = hipn;
        int yA = yL - 2;
        float aV = 0.f, bV = 0.f;
        if ((unsigned)yA < 256u && yA >= Y0 - 2) {
            int ylo = (yA - 2 > 0) ? yA - 2 : 0, yhi = (yA + 2 < 255) ? yA + 2 : 255;
            float inv1 = cxr / (float)(yhi - ylo + 1);
            float mI = meanI[yA * 256 + t], vI = varI[yA * 256 + t];
            float mp = vp * inv1, mip = vip * inv1;
            float cov = mip - mI * mp;
            aV = cov / (vI + 0.01f);
            bV = mp - aV * mI;
        }
        Arow[t + 2] = aV;
        Brow[t + 2] = bV;
        __syncthreads();
        float han = Arow[t] + Arow[t + 1] + Arow[t + 2] + Arow[t + 3] + Arow[t + 4];
        float hbn = Brow[t] + Brow[t + 1] + Brow[t + 2] + Brow[t + 3] + Brow[t + 4];
        va += han - ha[0];  vb += hbn - hb[0];
        ha[0] = ha[1]; ha[1] = ha[2]; ha[2] = ha[3]; ha[3] = ha[4]; ha[4] = han;
        hb[0] = hb[1]; hb[1] = hb[2]; hb[2] = hb[3]; hb[3] = hb[4]; hb[4] = hbn;
        int yo = yL - 4;
        if (yo >= Y0 && yo < Y0 + 64 && (unsigned)yo < 256u) {
            int ylo = (yo - 2 > 0) ? yo - 2 : 0, yhi = (yo + 2 < 255) ? yo + 2 : 255;
            float inv2 = cxr / (float)(yhi - ylo + 1);
            float I = guide[yo * 256 + t];
            filt[(size_t)c * P2 + yo * 256 + t] = __float2bfloat16((va * I + vb) * inv2);
        }
    }
}

// ---------------------------------------------------------------- transpose bf16 [c][p] -> chunk-planar
__global__ void transpose_cp(const __hip_bfloat16* __restrict__ filt,
                             __hip_bfloat16* __restrict__ filtp) {
    __shared__ __hip_bfloat16 T[8][1032];
    int tid = threadIdx.x;
    int p0 = blockIdx.x * 1024;
    int cg = blockIdx.y;
    for (int i = tid; i < 4096; i += 256) {
        int r = i >> 9, pl2 = (i & 511) * 2;
        unsigned v = *(const unsigned*)&filt[(size_t)(cg * 8 + r) * P2 + p0 + pl2];
        *(unsigned*)&T[r][pl2] = v;
    }
    __syncthreads();
    for (int pl = tid; pl < 1024; pl += 256) {
        union { __hip_bfloat16 h[8]; f32x4 v; } u;
#pragma unroll
        for (int j = 0; j < 8; j++) u.h[j] = T[j][pl];
        *(f32x4*)&filtp[((size_t)cg * P2 + p0 + pl) * 8] = u.v;
    }
}

// ---------------------------------------------------------------- sigmoid head finalize
__global__ void sigmoid_head(const float* __restrict__ haccum, const float* __restrict__ bm,
                             float* __restrict__ out) {
    int p = blockIdx.x * 256 + threadIdx.x;
    out[p] = 1.0f / (1.0f + expf(-(haccum[p] + bm[0])));
}

// ---------------------------------------------------------------- launch
extern "C" void kernel_launch(void* const* d_in, const int* in_sizes, int n_in,
                              void* d_out, int out_size, void* d_ws, size_t ws_size,
                              hipStream_t stream) {
    const float* fg   = (const float*)d_in[0];
    const float* bg   = (const float*)d_in[1];
    const float* mask = (const float*)d_in[2];
    const float* feat = (const float*)d_in[3];
    const float* w1   = (const float*)d_in[4];
    const float* b1   = (const float*)d_in[5];
    const float* w2   = (const float*)d_in[6];
    const float* b2   = (const float*)d_in[7];
    const float* w3   = (const float*)d_in[8];
    const float* b3   = (const float*)d_in[9];
    const float* wm   = (const float*)d_in[10];
    const float* bm   = (const float*)d_in[11];
    float* out = (float*)d_out;
    char* w8 = (char*)d_ws;

    __half* pbuf          = (__half*)w8;                         // 2 x 33,554,432 B (K-split partials)
    __hip_bfloat16* filtp = (__hip_bfloat16*)(w8 + 33554432);    // aliases pbuf half 1 (read before overwrite? NO)
    // NOTE: pbuf half 1 occupies [33.5M, 67M). filtp must NOT alias it while gf still needs it.
    // transpose writes filtp only AFTER gf_stream finished reading pbuf -> safe to alias.
    __hip_bfloat16* xp    = (__hip_bfloat16*)(w8 + 67108864);    // 37,748,736 B
    __hip_bfloat16* filt  = (__hip_bfloat16*)(w8 + 67108864);    // alias xp (dead after conv1)
    __hip_bfloat16* y1p   = (__hip_bfloat16*)(w8 + 104857600);   // 34,611,200 B
    __hip_bfloat16* wpk2  = (__hip_bfloat16*)(w8 + 139468800);   // 3,276,800 B
    __hip_bfloat16* wpk1  = (__hip_bfloat16*)(w8 + 142745600);   // 147,456 B
    __hip_bfloat16* wpk3  = (__hip_bfloat16*)(w8 + 142893056);   // 131,072 B
    float* guide  = (float*)(w8 + 143024128);
    float* meanI  = guide + P2;
    float* varI   = meanI + P2;
    float* haccum = varI + P2;

    // 1. merged prep (upsample + guide/stats + border + haccum-zero + repacks)
    prep_mega<<<10533, 256, 0, stream>>>(mask, fg, bg, feat, w1, w2, w3,
                                         xp, guide, meanI, varI, wpk1, wpk2, wpk3, y1p, haccum);
    // 2. conv1 (1x1 MFMA, merged oh) -> y1p
    mfma_1x1<0><<<512, 256, 0, stream>>>(xp, wpk1, b1, y1p, 9, nullptr, nullptr);
    // 3. conv2 (5x5 MFMA, K-split) -> pbuf (2 fp16 partial planes)
    conv5x5_mfma<<<dim3(16, 32, 4), 128, 0, stream>>>(y1p, wpk2, b2, pbuf);
    // 4. guided filter (sums partials + relu) -> filt (bf16 [c][p])
    gf_stream<<<dim3(4, 256), 256, 0, stream>>>(pbuf, guide, meanI, varI, filt);
    // 5. transpose -> filtp (overwrites pbuf half 1 — safe, gf done)
    transpose_cp<<<dim3(64, 32), 256, 0, stream>>>(filt, filtp);
    // 6. conv3 (1x1 MFMA merged, fused head partials) -> out+P2 & haccum
    mfma_1x1<1><<<512, 256, 0, stream>>>(filtp, wpk3, b3, out + P2, 8, wm, haccum);
    // 7. sigmoid head -> out[0..P2)
    sigmoid_head<<<256, 256, 0, stream>>>(haccum, bm, out);
}

// Round 10
// 431.541 us; speedup vs baseline: 1.0567x; 1.0567x over previous
//
#include <hip/hip_runtime.h>
#include <hip/hip_bf16.h>
#include <hip/hip_fp16.h>
#include <math.h>

// GuidedUpsampleUnitGF — R10: R8's proven conv2 core (180us; R9 K-split was register-bound,
// not grid-bound — reverted) + R9's prep_mega launch fusion (7 launches, -18us).

#define P2 65536            // 256*256 pixels
#define PADW 260            // padded image width/height for conv2 (halo 2)

typedef short  frag8  __attribute__((ext_vector_type(8)));   // 8 bf16 (4 VGPRs)
typedef float  f32x4  __attribute__((ext_vector_type(4)));

__device__ __forceinline__ void load16_lds(const void* gsrc, void* lds) {
    __builtin_amdgcn_global_load_lds((const __attribute__((address_space(1))) void*)gsrc,
                                     (__attribute__((address_space(3))) void*)lds, 16, 0, 0);
}

// bilinear 2x upsample coords (half-pixel centers, edge-clamped {0.25,0.75})
struct BilC { int y0, y1, x0, x1; float wy0, wy1, wx0, wx1; };
__device__ __forceinline__ BilC bil_coords(int oy, int ox) {
    BilC c;
    int m = oy >> 1;
    if ((oy & 1) == 0) { c.y0 = (m > 0) ? m - 1 : 0; c.y1 = m; c.wy0 = 0.25f; }
    else               { c.y0 = m; c.y1 = (m < 127) ? m + 1 : 127; c.wy0 = 0.75f; }
    c.wy1 = 1.0f - c.wy0;
    int n = ox >> 1;
    if ((ox & 1) == 0) { c.x0 = (n > 0) ? n - 1 : 0; c.x1 = n; c.wx0 = 0.25f; }
    else               { c.x0 = n; c.x1 = (n < 127) ? n + 1 : 127; c.wx0 = 0.75f; }
    c.wx1 = 1.0f - c.wx0;
    return c;
}
__device__ __forceinline__ float bil_eval(const float* __restrict__ src, const BilC& c) {
    return c.wy0 * (c.wx0 * src[c.y0 * 128 + c.x0] + c.wx1 * src[c.y0 * 128 + c.x1])
         + c.wy1 * (c.wx0 * src[c.y1 * 128 + c.x0] + c.wx1 * src[c.y1 * 128 + c.x1]);
}

// ---------------------------------------------------------------- merged prep mega-kernel
// b ranges: [0,9216) upsample_x | [9216,9472) guide+stats | [9472,9601) border zero
//           [9601,9665) haccum zero | [9665,10465) w2 repack | [10465,10501) w1 | [10501,10533) w3
__global__ __launch_bounds__(256) void prep_mega(const float* __restrict__ mask,
                                                 const float* __restrict__ fg,
                                                 const float* __restrict__ bg,
                                                 const float* __restrict__ feat,
                                                 const float* __restrict__ w1,
                                                 const float* __restrict__ w2,
                                                 const float* __restrict__ w3,
                                                 __hip_bfloat16* __restrict__ xp,
                                                 float* __restrict__ guide,
                                                 float* __restrict__ meanI,
                                                 float* __restrict__ varI,
                                                 __hip_bfloat16* __restrict__ wpk1,
                                                 __hip_bfloat16* __restrict__ wpk2,
                                                 __hip_bfloat16* __restrict__ wpk3,
                                                 __hip_bfloat16* __restrict__ y1p,
                                                 float* __restrict__ haccum) {
    __shared__ float G[20 * 21];
    int b = blockIdx.x;
    int tid = threadIdx.x;
    if (b < 9216) {                                    // upsample -> xp [36][P2][8]
        int chunk = b >> 8;
        int p = (b & 255) * 256 + tid;
        union { __hip_bfloat16 h[8]; f32x4 v; } u;
        if (chunk >= 33) {
            f32x4 z = {0.f, 0.f, 0.f, 0.f};
            *(f32x4*)&xp[((size_t)chunk * P2 + p) * 8] = z;
            return;
        }
        BilC bc = bil_coords(p >> 8, p & 255);
#pragma unroll
        for (int j = 0; j < 8; j++) {
            int c = chunk * 8 + j;
            float v = 0.f;
            if (c < 263) {
                const float* src = (c == 0) ? mask
                                 : (c < 4)  ? fg + (c - 1) * 16384
                                 : (c < 7)  ? bg + (c - 4) * 16384
                                 :            feat + (c - 7) * 16384;
                v = bil_eval(src, bc);
            }
            u.h[j] = __float2bfloat16(v);
        }
        *(f32x4*)&xp[((size_t)chunk * P2 + p) * 8] = u.v;
    } else if (b < 9472) {                             // fused guide + stats
        int bb = b - 9216;
        int gx0 = (bb & 15) * 16, gy0 = (bb >> 4) * 16;
        for (int i = tid; i < 400; i += 256) {
            int r = i / 20, c = i - r * 20;
            int gy = gy0 + r - 2, gx = gx0 + c - 2;
            float v = 0.f;
            if ((unsigned)gy < 256u && (unsigned)gx < 256u) {
                BilC bc = bil_coords(gy, gx);
                v = (bil_eval(fg, bc) + bil_eval(fg + 16384, bc) + bil_eval(fg + 32768, bc))
                    * (128.0f / 3.0f);
            }
            G[r * 21 + c] = v;
        }
        __syncthreads();
        int ty = tid >> 4, tx = tid & 15;
        int gy = gy0 + ty, gx = gx0 + tx;
        float s = 0.f, ss = 0.f;
#pragma unroll
        for (int dy = 0; dy < 5; dy++)
#pragma unroll
            for (int dx = 0; dx < 5; dx++) {
                float v = G[(ty + dy) * 21 + tx + dx];
                s += v; ss += v * v;
            }
        int cy = ((gy + 2 < 255) ? gy + 2 : 255) - ((gy - 2 > 0) ? gy - 2 : 0) + 1;
        int cx = ((gx + 2 < 255) ? gx + 2 : 255) - ((gx - 2 > 0) ? gx - 2 : 0) + 1;
        float inv = 1.0f / (float)(cy * cx);
        float m = s * inv;
        guide[gy * 256 + gx] = G[(ty + 2) * 21 + tx + 2];
        meanI[gy * 256 + gx] = m;
        varI[gy * 256 + gx]  = ss * inv - m * m;
    } else if (b < 9601) {                             // border zero: 2064 px * 16 chunks
        int idx = (b - 9472) * 256 + tid;
        if (idx >= 33024) return;
        int pid = idx >> 4, chunk = idx & 15;
        int py, px;
        if (pid < 520)       { py = pid / 260;               px = pid - py * 260; }
        else if (pid < 1040) { int t = pid - 520; int r = t / 260; py = 258 + r; px = t - r * 260; }
        else                 { int t = pid - 1040; int r = t >> 2; int c = t & 3;
                               py = 2 + r; px = (c < 2) ? c : 256 + c; }
        f32x4 z = {0.f, 0.f, 0.f, 0.f};
        f32x4* dst = (f32x4*)&y1p[((size_t)py * PADW + px) * 256 + chunk * 16];
        dst[0] = z; dst[1] = z;
    } else if (b < 9665) {                             // haccum zero
        int idx = (b - 9601) * 256 + tid;
        f32x4 z = {0.f, 0.f, 0.f, 0.f};
        *(f32x4*)&haccum[idx * 4] = z;
    } else if (b < 10465) {                            // w2 -> [tap][ict][nb][lane][8]
        int idx = (b - 9665) * 256 + tid;              // 204800
        int lane = idx & 63;
        int nb = (idx >> 6) & 15;
        int kt = (idx >> 10) & 7;
        int t  = idx >> 13;
        int oc = nb * 16 + (lane & 15);
        int ic0 = kt * 32 + (lane >> 4) * 8;
        union { __hip_bfloat16 h[8]; f32x4 v; } u;
#pragma unroll
        for (int j = 0; j < 8; j++)
            u.h[j] = __float2bfloat16(w2[(oc * 256 + ic0 + j) * 25 + t]);
        *(f32x4*)&wpk2[(size_t)idx * 8] = u.v;
    } else {
        const float* W; __hip_bfloat16* dst; int K, KT, idx;
        if (b < 10501) { W = w1; dst = wpk1; K = 263; KT = 9; idx = (b - 10465) * 256 + tid; }
        else           { W = w3; dst = wpk3; K = 256; KT = 8; idx = (b - 10501) * 256 + tid; }
        if (idx >= KT * 16 * 64) return;
        int lane = idx & 63;
        int nbg = (idx >> 6) & 15;
        int kt = idx >> 10;
        int oc = nbg * 16 + (lane & 15);
        int ic0 = kt * 32 + (lane >> 4) * 8;
        union { __hip_bfloat16 h[8]; f32x4 v; } u;
#pragma unroll
        for (int j = 0; j < 8; j++) {
            int ic = ic0 + j;
            u.h[j] = (ic < K) ? __float2bfloat16(W[(size_t)oc * K + ic]) : __float2bfloat16(0.f);
        }
        *(f32x4*)&dst[(size_t)idx * 8] = u.v;
    }
}

// ---------------------------------------------------------------- 1x1 MFMA GEMM, merged oh
// block: 128 px x 256 oc; 4 waves, each 8M x 4N. grid (512).
template<int MODE>
__global__ __launch_bounds__(256) void mfma_1x1(const __hip_bfloat16* __restrict__ xch,
                                                const __hip_bfloat16* __restrict__ wpk,
                                                const float* __restrict__ bias,
                                                void* __restrict__ outp, int KT,
                                                const float* __restrict__ wmv,
                                                float* __restrict__ haccum) {
    __shared__ __align__(16) char smem[MODE == 0 ? 67584 : 49152];
    __hip_bfloat16* Asm0 = (__hip_bfloat16*)smem;                 // [2][128*32]   16 KB
    __hip_bfloat16* Bsm0 = (__hip_bfloat16*)(smem + 16384);       // [2][16*64*8]  32 KB
    const int tid = threadIdx.x;
    const int wave = tid >> 6, lane = tid & 63;
    const int q = lane >> 4, m16 = lane & 15;
    const int wn = wave;
    const int pb = blockIdx.x * 128;

    f32x4 acc[8][4] = {};

    auto stA = [&](int kt, int buf) {
#pragma unroll
        for (int it = 0; it < 2; it++) {
            int chb = it * 256 + wave * 64;
            int ch = chb + lane;
            int px = ch >> 2, oct = ch & 3;
            const __hip_bfloat16* src = xch + ((size_t)(kt * 4 + oct) * P2 + pb + px) * 8;
            load16_lds(src, &Asm0[(size_t)buf * 4096 + chb * 8]);
        }
    };
    auto stB = [&](int kt, int buf) {
#pragma unroll
        for (int it = 0; it < 4; it++) {
            int chb = it * 256 + wave * 64;
            int ch = chb + lane;
            int nb = ch >> 6, l = ch & 63;
            const __hip_bfloat16* src = wpk + (((size_t)kt * 16 + nb) * 64 + l) * 8;
            load16_lds(src, &Bsm0[(size_t)buf * 8192 + chb * 8]);
        }
    };
    stA(0, 0); stB(0, 0);
    int buf = 0;
    for (int kt = 0; kt < KT; kt++) {
        __syncthreads();
        if (kt + 1 < KT) { stA(kt + 1, buf ^ 1); stB(kt + 1, buf ^ 1); }
        frag8 a[8], b[4];
#pragma unroll
        for (int i = 0; i < 8; i++)
            a[i] = *(const frag8*)&Asm0[(size_t)buf * 4096 + (i * 16 + m16) * 32 + q * 8];
#pragma unroll
        for (int j = 0; j < 4; j++)
            b[j] = *(const frag8*)&Bsm0[(size_t)buf * 8192 + ((wn * 4 + j) * 64 + lane) * 8];
#pragma unroll
        for (int i = 0; i < 8; i++)
#pragma unroll
            for (int j = 0; j < 4; j++)
                acc[i][j] = __builtin_amdgcn_mfma_f32_16x16x32_bf16(a[i], b[j], acc[i][j], 0, 0, 0);
        buf ^= 1;
    }
    if (MODE == 0) {
        __syncthreads();
        __hip_bfloat16* Ct = (__hip_bfloat16*)smem;
#pragma unroll
        for (int j = 0; j < 4; j++) {
            int ocr = (wn * 4 + j) * 16 + m16;
            float bj = bias[ocr];
#pragma unroll
            for (int i = 0; i < 8; i++) {
                f32x4 v = acc[i][j];
#pragma unroll
                for (int e = 0; e < 4; e++) {
                    int pxr = i * 16 + q * 4 + e;
                    float tv = v[e] + bj;
                    Ct[pxr * 264 + ocr] = __float2bfloat16(tv > 0.f ? tv : 0.f);
                }
            }
        }
        __syncthreads();
        __hip_bfloat16* y1p = (__hip_bfloat16*)outp;
        int colr = (tid & 31) * 8;
#pragma unroll
        for (int it = 0; it < 16; it++) {
            int pxr = it * 8 + (tid >> 5);
            int pix = pb + pxr;
            int py = pix >> 8, px = pix & 255;
            f32x4 val = *(f32x4*)&Ct[pxr * 264 + colr];
            *(f32x4*)&y1p[((size_t)(py + 2) * PADW + px + 2) * 256 + colr] = val;
        }
    } else {
        float* outf = (float*)outp;
        float hpart[8][4] = {};
#pragma unroll
        for (int j = 0; j < 4; j++) {
            int oc = (wn * 4 + j) * 16 + m16;
            float bj = bias[oc];
            float wj = wmv[oc];
#pragma unroll
            for (int i = 0; i < 8; i++) {
                f32x4 v = acc[i][j];
#pragma unroll
                for (int e = 0; e < 4; e++) {
                    float tv = v[e] + bj;
                    tv = tv > 0.f ? tv : 0.f;
                    v[e] = tv;
                    hpart[i][e] += wj * tv;
                }
                *(f32x4*)&outf[(size_t)oc * P2 + pb + i * 16 + q * 4] = v;
            }
        }
#pragma unroll
        for (int i = 0; i < 8; i++)
#pragma unroll
            for (int e = 0; e < 4; e++) {
                float s = hpart[i][e];
                s += __shfl_xor(s, 1);
                s += __shfl_xor(s, 2);
                s += __shfl_xor(s, 4);
                s += __shfl_xor(s, 8);
                if (m16 == 0)
                    atomicAdd(&haccum[pb + i * 16 + q * 4 + e], s);
            }
    }
}

// ---------------------------------------------------------------- conv2: 5x5 MFMA (exact R6/R8 core)
// block: 128 threads = 2 waves; each wave 4M (16px strips) x 8N (128 oc).
// A: LDS double-buffer (global_load_lds), barrier only at ic-tile flip.
// B: global->register, one-step ping-pong prefetch (L1/L2-resident weights).
__global__ __launch_bounds__(128, 2) void conv5x5_mfma(const __hip_bfloat16* __restrict__ y1p,
                                                       const __hip_bfloat16* __restrict__ wpk,
                                                       const float* __restrict__ bias,
                                                       __half* __restrict__ pf) {
    __shared__ __align__(16) __hip_bfloat16 Asm[2][12 * 20 * 32];  // 2 x 15360 B
    const int tid = threadIdx.x;
    const int wave = tid >> 6;
    const int lane = tid & 63;
    const int q = lane >> 4;
    const int m16 = lane & 15;
    const int bx = blockIdx.x, by = blockIdx.y, oh = blockIdx.z;

    f32x4 acc[4][8] = {};

    auto stageA = [&](int ict, int buf) {
#pragma unroll
        for (int g = 0; g < 8; g++) {
            int grp = g * 2 + wave;
            if (grp >= 15) break;
            int chb = grp * 64;
            int ch = chb + lane;
            int oct = ch & 3, pl = ch >> 2;
            int pc = pl % 20, pr = pl / 20;
            const __hip_bfloat16* src =
                y1p + (size_t)((by * 8 + pr) * PADW + bx * 16 + pc) * 256 + ict * 32 + oct * 8;
            load16_lds(src, &Asm[buf][chb * 8]);
        }
    };
    auto loadB = [&](int s, frag8* dst) {
        int ict = s / 25, tap = s - ict * 25;
        const __hip_bfloat16* base =
            wpk + ((size_t)((tap * 8 + ict) * 16 + oh * 8) * 64 + lane) * 8;
#pragma unroll
        for (int j = 0; j < 8; j++)
            dst[j] = *(const frag8*)(base + (size_t)j * 512);
    };

    frag8 bA[8], bB[8];
    stageA(0, 0);
    loadB(0, bA);
    int abuf = 0;

    auto step = [&](int s, frag8* bcur, frag8* bnxt) {
        int ict = s / 25, tap = s - ict * 25;
        if (tap == 0) __syncthreads();
        if (s + 1 < 200) loadB(s + 1, bnxt);
        if (tap == 24 && ict < 7) stageA(ict + 1, abuf ^ 1);
        int dy = tap / 5, dx = tap - dy * 5;
        frag8 a[4];
#pragma unroll
        for (int i = 0; i < 4; i++)
            a[i] = *(const frag8*)&Asm[abuf][((wave * 4 + i + dy) * 20 + m16 + dx) * 32 + q * 8];
#pragma unroll
        for (int i = 0; i < 4; i++)
#pragma unroll
            for (int j = 0; j < 8; j++)
                acc[i][j] = __builtin_amdgcn_mfma_f32_16x16x32_bf16(a[i], bcur[j], acc[i][j], 0, 0, 0);
        if (tap == 24) abuf ^= 1;
    };
    for (int s = 0; s < 200; s += 2) { step(s, bA, bB); step(s + 1, bB, bA); }

    // epilogue: fp16 out (relu), 8B stores
#pragma unroll
    for (int j = 0; j < 8; j++) {
        int oc = oh * 128 + j * 16 + m16;
        float bj = bias[oc];
#pragma unroll
        for (int i = 0; i < 4; i++) {
            int r = wave * 4 + i;
            f32x4 v = acc[i][j];
            union { __half h[4]; double d; } u;
#pragma unroll
            for (int e = 0; e < 4; e++) {
                float t = v[e] + bj;
                u.h[e] = __float2half(t > 0.f ? t : 0.f);
            }
            *(double*)&pf[(size_t)oc * P2 + (by * 8 + r) * 256 + bx * 16 + q * 4] = u.d;
        }
    }
}

// ---------------------------------------------------------------- guided filter: streaming separable
__global__ __launch_bounds__(256) void gf_stream(const __half* __restrict__ p,
                                                 const float* __restrict__ guide,
                                                 const float* __restrict__ meanI,
                                                 const float* __restrict__ varI,
                                                 __hip_bfloat16* __restrict__ filt) {
    __shared__ float Prow[260], IProw[260], Arow[260], Brow[260];
    const int t = threadIdx.x;
    const int c = blockIdx.y;
    const int Y0 = blockIdx.x * 64;
    const __half* pc = p + (size_t)c * P2;
    if (t < 4) {
        int e = (t < 2) ? t : 256 + t;
        Prow[e] = 0.f; IProw[e] = 0.f; Arow[e] = 0.f; Brow[e] = 0.f;
    }
    int xlo = (t - 2 > 0) ? t - 2 : 0, xhi = (t + 2 < 255) ? t + 2 : 255;
    const float cxr = 1.0f / (float)(xhi - xlo + 1);
    float hp[5] = {0, 0, 0, 0, 0}, hip[5] = {0, 0, 0, 0, 0};
    float ha[5] = {0, 0, 0, 0, 0}, hb[5] = {0, 0, 0, 0, 0};
    float vp = 0.f, vip = 0.f, va = 0.f, vb = 0.f;
    __syncthreads();
    for (int s = 0; s < 72; s++) {
        int yL = Y0 - 4 + s;
        bool okL = ((unsigned)yL < 256u);
        if (okL) {
            float pv = __half2float(pc[yL * 256 + t]);
            Prow[t + 2] = pv;
            IProw[t + 2] = guide[yL * 256 + t] * pv;
        }
        __syncthreads();
        float hpn = 0.f, hipn = 0.f;
        if (okL) {
            hpn  = Prow[t] + Prow[t + 1] + Prow[t + 2] + Prow[t + 3] + Prow[t + 4];
            hipn = IProw[t] + IProw[t + 1] + IProw[t + 2] + IProw[t + 3] + IProw[t + 4];
        }
        vp += hpn - hp[0];  vip += hipn - hip[0];
        hp[0] = hp[1]; hp[1] = hp[2]; hp[2] = hp[3]; hp[3] = hp[4]; hp[4] = hpn;
        hip[0] = hip[1]; hip[1] = hip[2]; hip[2] = hip[3]; hip[3] = hip[4]; hip[4] = hipn;
        int yA = yL - 2;
        float aV = 0.f, bV = 0.f;
        if ((unsigned)yA < 256u && yA >= Y0 - 2) {
            int ylo = (yA - 2 > 0) ? yA - 2 : 0, yhi = (yA + 2 < 255) ? yA + 2 : 255;
            float inv1 = cxr / (float)(yhi - ylo + 1);
            float mI = meanI[yA * 256 + t], vI = varI[yA * 256 + t];
            float mp = vp * inv1, mip = vip * inv1;
            float cov = mip - mI * mp;
            aV = cov / (vI + 0.01f);
            bV = mp - aV * mI;
        }
        Arow[t + 2] = aV;
        Brow[t + 2] = bV;
        __syncthreads();
        float han = Arow[t] + Arow[t + 1] + Arow[t + 2] + Arow[t + 3] + Arow[t + 4];
        float hbn = Brow[t] + Brow[t + 1] + Brow[t + 2] + Brow[t + 3] + Brow[t + 4];
        va += han - ha[0];  vb += hbn - hb[0];
        ha[0] = ha[1]; ha[1] = ha[2]; ha[2] = ha[3]; ha[3] = ha[4]; ha[4] = han;
        hb[0] = hb[1]; hb[1] = hb[2]; hb[2] = hb[3]; hb[3] = hb[4]; hb[4] = hbn;
        int yo = yL - 4;
        if (yo >= Y0 && yo < Y0 + 64 && (unsigned)yo < 256u) {
            int ylo = (yo - 2 > 0) ? yo - 2 : 0, yhi = (yo + 2 < 255) ? yo + 2 : 255;
            float inv2 = cxr / (float)(yhi - ylo + 1);
            float I = guide[yo * 256 + t];
            filt[(size_t)c * P2 + yo * 256 + t] = __float2bfloat16((va * I + vb) * inv2);
        }
    }
}

// ---------------------------------------------------------------- transpose bf16 [c][p] -> chunk-planar
__global__ void transpose_cp(const __hip_bfloat16* __restrict__ filt,
                             __hip_bfloat16* __restrict__ filtp) {
    __shared__ __hip_bfloat16 T[8][1032];
    int tid = threadIdx.x;
    int p0 = blockIdx.x * 1024;
    int cg = blockIdx.y;
    for (int i = tid; i < 4096; i += 256) {
        int r = i >> 9, pl2 = (i & 511) * 2;
        unsigned v = *(const unsigned*)&filt[(size_t)(cg * 8 + r) * P2 + p0 + pl2];
        *(unsigned*)&T[r][pl2] = v;
    }
    __syncthreads();
    for (int pl = tid; pl < 1024; pl += 256) {
        union { __hip_bfloat16 h[8]; f32x4 v; } u;
#pragma unroll
        for (int j = 0; j < 8; j++) u.h[j] = T[j][pl];
        *(f32x4*)&filtp[((size_t)cg * P2 + p0 + pl) * 8] = u.v;
    }
}

// ---------------------------------------------------------------- sigmoid head finalize
__global__ void sigmoid_head(const float* __restrict__ haccum, const float* __restrict__ bm,
                             float* __restrict__ out) {
    int p = blockIdx.x * 256 + threadIdx.x;
    out[p] = 1.0f / (1.0f + expf(-(haccum[p] + bm[0])));
}

// ---------------------------------------------------------------- launch
extern "C" void kernel_launch(void* const* d_in, const int* in_sizes, int n_in,
                              void* d_out, int out_size, void* d_ws, size_t ws_size,
                              hipStream_t stream) {
    const float* fg   = (const float*)d_in[0];
    const float* bg   = (const float*)d_in[1];
    const float* mask = (const float*)d_in[2];
    const float* feat = (const float*)d_in[3];
    const float* w1   = (const float*)d_in[4];
    const float* b1   = (const float*)d_in[5];
    const float* w2   = (const float*)d_in[6];
    const float* b2   = (const float*)d_in[7];
    const float* w3   = (const float*)d_in[8];
    const float* b3   = (const float*)d_in[9];
    const float* wm   = (const float*)d_in[10];
    const float* bm   = (const float*)d_in[11];
    float* out = (float*)d_out;
    char* w8 = (char*)d_ws;

    __half* pbuf          = (__half*)w8;                         // 33,554,432 B (conv2 out fp16 [c][p])
    __hip_bfloat16* filtp = (__hip_bfloat16*)(w8 + 33554432);    // 33,554,432 B [32][P2][8]
    __hip_bfloat16* xp    = (__hip_bfloat16*)(w8 + 67108864);    // 37,748,736 B
    __hip_bfloat16* filt  = (__hip_bfloat16*)(w8 + 67108864);    // alias xp (dead after conv1)
    __hip_bfloat16* y1p   = (__hip_bfloat16*)(w8 + 104857600);   // 34,611,200 B
    __hip_bfloat16* wpk2  = (__hip_bfloat16*)(w8 + 139468800);   // 3,276,800 B
    __hip_bfloat16* wpk1  = (__hip_bfloat16*)(w8 + 142745600);   // 147,456 B
    __hip_bfloat16* wpk3  = (__hip_bfloat16*)(w8 + 142893056);   // 131,072 B
    float* guide  = (float*)(w8 + 143024128);
    float* meanI  = guide + P2;
    float* varI   = meanI + P2;
    float* haccum = varI + P2;

    // 1. merged prep (upsample + guide/stats + border + haccum-zero + repacks)
    prep_mega<<<10533, 256, 0, stream>>>(mask, fg, bg, feat, w1, w2, w3,
                                         xp, guide, meanI, varI, wpk1, wpk2, wpk3, y1p, haccum);
    // 2. conv1 (1x1 MFMA, merged oh) -> y1p
    mfma_1x1<0><<<512, 256, 0, stream>>>(xp, wpk1, b1, y1p, 9, nullptr, nullptr);
    // 3. conv2 (5x5 MFMA, R8 core) -> pbuf (fp16 [c][p])
    conv5x5_mfma<<<dim3(16, 32, 2), 128, 0, stream>>>(y1p, wpk2, b2, pbuf);
    // 4. guided filter -> filt (bf16 [c][p])
    gf_stream<<<dim3(4, 256), 256, 0, stream>>>(pbuf, guide, meanI, varI, filt);
    // 5. transpose -> filtp
    transpose_cp<<<dim3(64, 32), 256, 0, stream>>>(filt, filtp);
    // 6. conv3 (1x1 MFMA merged, fused head partials) -> out+P2 & haccum
    mfma_1x1<1><<<512, 256, 0, stream>>>(filtp, wpk3, b3, out + P2, 8, wm, haccum);
    // 7. sigmoid head -> out[0..P2)
    sigmoid_head<<<256, 256, 0, stream>>>(haccum, bm, out);
}

// Round 11
// 429.159 us; speedup vs baseline: 1.0626x; 1.0056x over previous
//
#include <hip/hip_runtime.h>
#include <hip/hip_bf16.h>
#include <hip/hip_fp16.h>
#include <math.h>

// GuidedUpsampleUnitGF — R11: conv1 commuted with upsample (1x1 conv and bilinear are both
// linear): z = W1@x_lo + b1 at 128x128, then y1p = relu(bilinear_2x(z)). Kills the 37.7MB
// hi-res x round-trip and 3/4 of conv1's FLOPs. conv2/gf/transpose/conv3 unchanged from R10.

#define P2 65536            // 256*256 pixels
#define PLO 16384           // 128*128 pixels (lo-res)
#define PADW 260            // padded image width/height for conv2 (halo 2)

typedef short  frag8  __attribute__((ext_vector_type(8)));   // 8 bf16 (4 VGPRs)
typedef float  f32x4  __attribute__((ext_vector_type(4)));
typedef short  s16x8  __attribute__((ext_vector_type(8)));

__device__ __forceinline__ void load16_lds(const void* gsrc, void* lds) {
    __builtin_amdgcn_global_load_lds((const __attribute__((address_space(1))) void*)gsrc,
                                     (__attribute__((address_space(3))) void*)lds, 16, 0, 0);
}
__device__ __forceinline__ float bf2f(short s) {
    union { unsigned u; float f; } c;
    c.u = ((unsigned)(unsigned short)s) << 16;
    return c.f;
}

// bilinear 2x upsample coords (half-pixel centers, edge-clamped {0.25,0.75})
struct BilC { int y0, y1, x0, x1; float wy0, wy1, wx0, wx1; };
__device__ __forceinline__ BilC bil_coords(int oy, int ox) {
    BilC c;
    int m = oy >> 1;
    if ((oy & 1) == 0) { c.y0 = (m > 0) ? m - 1 : 0; c.y1 = m; c.wy0 = 0.25f; }
    else               { c.y0 = m; c.y1 = (m < 127) ? m + 1 : 127; c.wy0 = 0.75f; }
    c.wy1 = 1.0f - c.wy0;
    int n = ox >> 1;
    if ((ox & 1) == 0) { c.x0 = (n > 0) ? n - 1 : 0; c.x1 = n; c.wx0 = 0.25f; }
    else               { c.x0 = n; c.x1 = (n < 127) ? n + 1 : 127; c.wx0 = 0.75f; }
    c.wx1 = 1.0f - c.wx0;
    return c;
}
__device__ __forceinline__ float bil_eval(const float* __restrict__ src, const BilC& c) {
    return c.wy0 * (c.wx0 * src[c.y0 * 128 + c.x0] + c.wx1 * src[c.y0 * 128 + c.x1])
         + c.wy1 * (c.wx0 * src[c.y1 * 128 + c.x0] + c.wx1 * src[c.y1 * 128 + c.x1]);
}

// ---------------------------------------------------------------- merged prep mega-kernel
// b ranges: [0,2304) pack x_lo | [2304,2560) guide+stats | [2560,2689) border zero
//           [2689,2753) haccum zero | [2753,3553) w2 repack | [3553,3589) w1 | [3589,3621) w3
__global__ __launch_bounds__(256) void prep_mega(const float* __restrict__ mask,
                                                 const float* __restrict__ fg,
                                                 const float* __restrict__ bg,
                                                 const float* __restrict__ feat,
                                                 const float* __restrict__ w1,
                                                 const float* __restrict__ w2,
                                                 const float* __restrict__ w3,
                                                 __hip_bfloat16* __restrict__ xlo,
                                                 float* __restrict__ guide,
                                                 float* __restrict__ meanI,
                                                 float* __restrict__ varI,
                                                 __hip_bfloat16* __restrict__ wpk1,
                                                 __hip_bfloat16* __restrict__ wpk2,
                                                 __hip_bfloat16* __restrict__ wpk3,
                                                 __hip_bfloat16* __restrict__ y1p,
                                                 float* __restrict__ haccum) {
    __shared__ float G[20 * 21];
    int b = blockIdx.x;
    int tid = threadIdx.x;
    if (b < 2304) {                                    // pack lo-res x -> xlo [36][PLO][8] bf16
        int idx = b * 256 + tid;
        int chunk = idx >> 14;
        int px = idx & 16383;
        union { __hip_bfloat16 h[8]; f32x4 v; } u;
        if (chunk >= 33) {
            f32x4 z = {0.f, 0.f, 0.f, 0.f};
            *(f32x4*)&xlo[((size_t)chunk * PLO + px) * 8] = z;
            return;
        }
#pragma unroll
        for (int j = 0; j < 8; j++) {
            int c = chunk * 8 + j;
            float v = 0.f;
            if (c < 263) {
                const float* src = (c == 0) ? mask
                                 : (c < 4)  ? fg + (c - 1) * PLO
                                 : (c < 7)  ? bg + (c - 4) * PLO
                                 :            feat + (c - 7) * PLO;
                v = src[px];
            }
            u.h[j] = __float2bfloat16(v);
        }
        *(f32x4*)&xlo[((size_t)chunk * PLO + px) * 8] = u.v;
    } else if (b < 2560) {                             // fused guide + stats
        int bb = b - 2304;
        int gx0 = (bb & 15) * 16, gy0 = (bb >> 4) * 16;
        for (int i = tid; i < 400; i += 256) {
            int r = i / 20, c = i - r * 20;
            int gy = gy0 + r - 2, gx = gx0 + c - 2;
            float v = 0.f;
            if ((unsigned)gy < 256u && (unsigned)gx < 256u) {
                BilC bc = bil_coords(gy, gx);
                v = (bil_eval(fg, bc) + bil_eval(fg + PLO, bc) + bil_eval(fg + 2 * PLO, bc))
                    * (128.0f / 3.0f);
            }
            G[r * 21 + c] = v;
        }
        __syncthreads();
        int ty = tid >> 4, tx = tid & 15;
        int gy = gy0 + ty, gx = gx0 + tx;
        float s = 0.f, ss = 0.f;
#pragma unroll
        for (int dy = 0; dy < 5; dy++)
#pragma unroll
            for (int dx = 0; dx < 5; dx++) {
                float v = G[(ty + dy) * 21 + tx + dx];
                s += v; ss += v * v;
            }
        int cy = ((gy + 2 < 255) ? gy + 2 : 255) - ((gy - 2 > 0) ? gy - 2 : 0) + 1;
        int cx = ((gx + 2 < 255) ? gx + 2 : 255) - ((gx - 2 > 0) ? gx - 2 : 0) + 1;
        float inv = 1.0f / (float)(cy * cx);
        float m = s * inv;
        guide[gy * 256 + gx] = G[(ty + 2) * 21 + tx + 2];
        meanI[gy * 256 + gx] = m;
        varI[gy * 256 + gx]  = ss * inv - m * m;
    } else if (b < 2689) {                             // border zero: 2064 px * 16 chunks
        int idx = (b - 2560) * 256 + tid;
        if (idx >= 33024) return;
        int pid = idx >> 4, chunk = idx & 15;
        int py, px;
        if (pid < 520)       { py = pid / 260;               px = pid - py * 260; }
        else if (pid < 1040) { int t = pid - 520; int r = t / 260; py = 258 + r; px = t - r * 260; }
        else                 { int t = pid - 1040; int r = t >> 2; int c = t & 3;
                               py = 2 + r; px = (c < 2) ? c : 256 + c; }
        f32x4 z = {0.f, 0.f, 0.f, 0.f};
        f32x4* dst = (f32x4*)&y1p[((size_t)py * PADW + px) * 256 + chunk * 16];
        dst[0] = z; dst[1] = z;
    } else if (b < 2753) {                             // haccum zero
        int idx = (b - 2689) * 256 + tid;
        f32x4 z = {0.f, 0.f, 0.f, 0.f};
        *(f32x4*)&haccum[idx * 4] = z;
    } else if (b < 3553) {                             // w2 -> [tap][ict][nb][lane][8]
        int idx = (b - 2753) * 256 + tid;              // 204800
        int lane = idx & 63;
        int nb = (idx >> 6) & 15;
        int kt = (idx >> 10) & 7;
        int t  = idx >> 13;
        int oc = nb * 16 + (lane & 15);
        int ic0 = kt * 32 + (lane >> 4) * 8;
        union { __hip_bfloat16 h[8]; f32x4 v; } u;
#pragma unroll
        for (int j = 0; j < 8; j++)
            u.h[j] = __float2bfloat16(w2[(oc * 256 + ic0 + j) * 25 + t]);
        *(f32x4*)&wpk2[(size_t)idx * 8] = u.v;
    } else {
        const float* W; __hip_bfloat16* dst; int K, KT, idx;
        if (b < 3589) { W = w1; dst = wpk1; K = 263; KT = 9; idx = (b - 3553) * 256 + tid; }
        else          { W = w3; dst = wpk3; K = 256; KT = 8; idx = (b - 3589) * 256 + tid; }
        if (idx >= KT * 16 * 64) return;
        int lane = idx & 63;
        int nbg = (idx >> 6) & 15;
        int kt = idx >> 10;
        int oc = nbg * 16 + (lane & 15);
        int ic0 = kt * 32 + (lane >> 4) * 8;
        union { __hip_bfloat16 h[8]; f32x4 v; } u;
#pragma unroll
        for (int j = 0; j < 8; j++) {
            int ic = ic0 + j;
            u.h[j] = (ic < K) ? __float2bfloat16(W[(size_t)oc * K + ic]) : __float2bfloat16(0.f);
        }
        *(f32x4*)&dst[(size_t)idx * 8] = u.v;
    }
}

// ---------------------------------------------------------------- gemm_z: conv1 at lo-res
// z[oc][p_lo] = W1[oc]@x_lo[p_lo] + b1[oc]  (NO relu — applied after upsample).
// block: 128 px x 128 oc, 4 waves (wm,wn) each 4Mx4N; grid (128, 2). Out: bf16 chunk-planar
// [32][PLO][8] via LDS restage.
__global__ __launch_bounds__(256) void gemm_z(const __hip_bfloat16* __restrict__ xlo,
                                              const __hip_bfloat16* __restrict__ wpk,
                                              const float* __restrict__ bias,
                                              __hip_bfloat16* __restrict__ z) {
    __shared__ __align__(16) char smem[34816];
    __hip_bfloat16* Asm0 = (__hip_bfloat16*)smem;                 // [2][128*32] 16 KB
    __hip_bfloat16* Bsm0 = (__hip_bfloat16*)(smem + 16384);       // [2][8*64*8] 16 KB
    const int tid = threadIdx.x;
    const int wave = tid >> 6, lane = tid & 63;
    const int q = lane >> 4, m16 = lane & 15;
    const int wm = wave & 1, wn = wave >> 1;
    const int pb = blockIdx.x * 128, oh = blockIdx.y;

    f32x4 acc[4][4] = {};

    auto stA = [&](int kt, int buf) {
#pragma unroll
        for (int it = 0; it < 2; it++) {
            int chb = it * 256 + wave * 64;
            int ch = chb + lane;
            int px = ch >> 2, oct = ch & 3;
            const __hip_bfloat16* src = xlo + ((size_t)(kt * 4 + oct) * PLO + pb + px) * 8;
            load16_lds(src, &Asm0[(size_t)buf * 4096 + chb * 8]);
        }
    };
    auto stB = [&](int kt, int buf) {
#pragma unroll
        for (int it = 0; it < 2; it++) {
            int chb = it * 256 + wave * 64;
            int ch = chb + lane;
            int nb = ch >> 6, l = ch & 63;
            const __hip_bfloat16* src = wpk + (((size_t)kt * 16 + oh * 8 + nb) * 64 + l) * 8;
            load16_lds(src, &Bsm0[(size_t)buf * 4096 + chb * 8]);
        }
    };
    stA(0, 0); stB(0, 0);
    int buf = 0;
    for (int kt = 0; kt < 9; kt++) {
        __syncthreads();
        if (kt + 1 < 9) { stA(kt + 1, buf ^ 1); stB(kt + 1, buf ^ 1); }
        frag8 a[4], b[4];
#pragma unroll
        for (int i = 0; i < 4; i++)
            a[i] = *(const frag8*)&Asm0[(size_t)buf * 4096 + ((wm * 4 + i) * 16 + m16) * 32 + q * 8];
#pragma unroll
        for (int j = 0; j < 4; j++)
            b[j] = *(const frag8*)&Bsm0[(size_t)buf * 4096 + ((wn * 4 + j) * 64 + lane) * 8];
#pragma unroll
        for (int i = 0; i < 4; i++)
#pragma unroll
            for (int j = 0; j < 4; j++)
                acc[i][j] = __builtin_amdgcn_mfma_f32_16x16x32_bf16(a[i], b[j], acc[i][j], 0, 0, 0);
        buf ^= 1;
    }
    // restage: Ct[128 px][136], coalesced chunk-planar store
    __syncthreads();
    __hip_bfloat16* Ct = (__hip_bfloat16*)smem;
#pragma unroll
    for (int j = 0; j < 4; j++) {
        int ocr = (wn * 4 + j) * 16 + m16;
        float bj = bias[oh * 128 + ocr];
#pragma unroll
        for (int i = 0; i < 4; i++) {
            f32x4 v = acc[i][j];
#pragma unroll
            for (int e = 0; e < 4; e++) {
                int pxr = (wm * 4 + i) * 16 + q * 4 + e;
                Ct[pxr * 136 + ocr] = __float2bfloat16(v[e] + bj);   // no relu
            }
        }
    }
    __syncthreads();
    int colr = (tid & 15) * 8;
    int cg = oh * 16 + (tid & 15);
#pragma unroll
    for (int it = 0; it < 8; it++) {
        int pxr = it * 16 + (tid >> 4);
        f32x4 val = *(f32x4*)&Ct[pxr * 136 + colr];
        *(f32x4*)&z[((size_t)cg * PLO + pb + pxr) * 8] = val;
    }
}

// ---------------------------------------------------------------- upsample z -> y1p (relu)
// thread: (pixel, chunk-of-8ch). Stores 16B, 512B contiguous per pixel across 32 lanes.
__global__ __launch_bounds__(256) void upsample_y1(const __hip_bfloat16* __restrict__ z,
                                                   __hip_bfloat16* __restrict__ y1p) {
    int t = blockIdx.x * 256 + threadIdx.x;
    int cg = t & 31;
    int p = t >> 5;
    int py = p >> 8, pxx = p & 255;
    BilC c = bil_coords(py, pxx);
    const __hip_bfloat16* zc = z + (size_t)cg * PLO * 8;
    s16x8 t00 = *(const s16x8*)&zc[(c.y0 * 128 + c.x0) * 8];
    s16x8 t01 = *(const s16x8*)&zc[(c.y0 * 128 + c.x1) * 8];
    s16x8 t10 = *(const s16x8*)&zc[(c.y1 * 128 + c.x0) * 8];
    s16x8 t11 = *(const s16x8*)&zc[(c.y1 * 128 + c.x1) * 8];
    union { __hip_bfloat16 h[8]; f32x4 v; } o;
#pragma unroll
    for (int j = 0; j < 8; j++) {
        float v = c.wy0 * (c.wx0 * bf2f(t00[j]) + c.wx1 * bf2f(t01[j]))
                + c.wy1 * (c.wx0 * bf2f(t10[j]) + c.wx1 * bf2f(t11[j]));
        o.h[j] = __float2bfloat16(v > 0.f ? v : 0.f);
    }
    *(f32x4*)&y1p[((size_t)(py + 2) * PADW + pxx + 2) * 256 + cg * 8] = o.v;
}

// ---------------------------------------------------------------- conv3 (1x1 MFMA merged oh)
// block: 128 px x 256 oc; 4 waves, each 8M x 4N; fp32 planar (+relu) out + fused mask-head
// partials (wm-weighted oc-reduction -> atomicAdd haccum).
template<int MODE>
__global__ __launch_bounds__(256) void mfma_1x1(const __hip_bfloat16* __restrict__ xch,
                                                const __hip_bfloat16* __restrict__ wpk,
                                                const float* __restrict__ bias,
                                                void* __restrict__ outp, int KT,
                                                const float* __restrict__ wmv,
                                                float* __restrict__ haccum) {
    __shared__ __align__(16) char smem[49152];
    __hip_bfloat16* Asm0 = (__hip_bfloat16*)smem;                 // [2][128*32]   16 KB
    __hip_bfloat16* Bsm0 = (__hip_bfloat16*)(smem + 16384);       // [2][16*64*8]  32 KB
    const int tid = threadIdx.x;
    const int wave = tid >> 6, lane = tid & 63;
    const int q = lane >> 4, m16 = lane & 15;
    const int wn = wave;
    const int pb = blockIdx.x * 128;

    f32x4 acc[8][4] = {};

    auto stA = [&](int kt, int buf) {
#pragma unroll
        for (int it = 0; it < 2; it++) {
            int chb = it * 256 + wave * 64;
            int ch = chb + lane;
            int px = ch >> 2, oct = ch & 3;
            const __hip_bfloat16* src = xch + ((size_t)(kt * 4 + oct) * P2 + pb + px) * 8;
            load16_lds(src, &Asm0[(size_t)buf * 4096 + chb * 8]);
        }
    };
    auto stB = [&](int kt, int buf) {
#pragma unroll
        for (int it = 0; it < 4; it++) {
            int chb = it * 256 + wave * 64;
            int ch = chb + lane;
            int nb = ch >> 6, l = ch & 63;
            const __hip_bfloat16* src = wpk + (((size_t)kt * 16 + nb) * 64 + l) * 8;
            load16_lds(src, &Bsm0[(size_t)buf * 8192 + chb * 8]);
        }
    };
    stA(0, 0); stB(0, 0);
    int buf = 0;
    for (int kt = 0; kt < KT; kt++) {
        __syncthreads();
        if (kt + 1 < KT) { stA(kt + 1, buf ^ 1); stB(kt + 1, buf ^ 1); }
        frag8 a[8], b[4];
#pragma unroll
        for (int i = 0; i < 8; i++)
            a[i] = *(const frag8*)&Asm0[(size_t)buf * 4096 + (i * 16 + m16) * 32 + q * 8];
#pragma unroll
        for (int j = 0; j < 4; j++)
            b[j] = *(const frag8*)&Bsm0[(size_t)buf * 8192 + ((wn * 4 + j) * 64 + lane) * 8];
#pragma unroll
        for (int i = 0; i < 8; i++)
#pragma unroll
            for (int j = 0; j < 4; j++)
                acc[i][j] = __builtin_amdgcn_mfma_f32_16x16x32_bf16(a[i], b[j], acc[i][j], 0, 0, 0);
        buf ^= 1;
    }
    {
        float* outf = (float*)outp;
        float hpart[8][4] = {};
#pragma unroll
        for (int j = 0; j < 4; j++) {
            int oc = (wn * 4 + j) * 16 + m16;
            float bj = bias[oc];
            float wj = wmv[oc];
#pragma unroll
            for (int i = 0; i < 8; i++) {
                f32x4 v = acc[i][j];
#pragma unroll
                for (int e = 0; e < 4; e++) {
                    float tv = v[e] + bj;
                    tv = tv > 0.f ? tv : 0.f;
                    v[e] = tv;
                    hpart[i][e] += wj * tv;
                }
                *(f32x4*)&outf[(size_t)oc * P2 + pb + i * 16 + q * 4] = v;
            }
        }
#pragma unroll
        for (int i = 0; i < 8; i++)
#pragma unroll
            for (int e = 0; e < 4; e++) {
                float s = hpart[i][e];
                s += __shfl_xor(s, 1);
                s += __shfl_xor(s, 2);
                s += __shfl_xor(s, 4);
                s += __shfl_xor(s, 8);
                if (m16 == 0)
                    atomicAdd(&haccum[pb + i * 16 + q * 4 + e], s);
            }
    }
}

// ---------------------------------------------------------------- conv2: 5x5 MFMA (R6/R8 core)
__global__ __launch_bounds__(128, 2) void conv5x5_mfma(const __hip_bfloat16* __restrict__ y1p,
                                                       const __hip_bfloat16* __restrict__ wpk,
                                                       const float* __restrict__ bias,
                                                       __half* __restrict__ pf) {
    __shared__ __align__(16) __hip_bfloat16 Asm[2][12 * 20 * 32];  // 2 x 15360 B
    const int tid = threadIdx.x;
    const int wave = tid >> 6;
    const int lane = tid & 63;
    const int q = lane >> 4;
    const int m16 = lane & 15;
    const int bx = blockIdx.x, by = blockIdx.y, oh = blockIdx.z;

    f32x4 acc[4][8] = {};

    auto stageA = [&](int ict, int buf) {
#pragma unroll
        for (int g = 0; g < 8; g++) {
            int grp = g * 2 + wave;
            if (grp >= 15) break;
            int chb = grp * 64;
            int ch = chb + lane;
            int oct = ch & 3, pl = ch >> 2;
            int pc = pl % 20, pr = pl / 20;
            const __hip_bfloat16* src =
                y1p + (size_t)((by * 8 + pr) * PADW + bx * 16 + pc) * 256 + ict * 32 + oct * 8;
            load16_lds(src, &Asm[buf][chb * 8]);
        }
    };
    auto loadB = [&](int s, frag8* dst) {
        int ict = s / 25, tap = s - ict * 25;
        const __hip_bfloat16* base =
            wpk + ((size_t)((tap * 8 + ict) * 16 + oh * 8) * 64 + lane) * 8;
#pragma unroll
        for (int j = 0; j < 8; j++)
            dst[j] = *(const frag8*)(base + (size_t)j * 512);
    };

    frag8 bA[8], bB[8];
    stageA(0, 0);
    loadB(0, bA);
    int abuf = 0;

    auto step = [&](int s, frag8* bcur, frag8* bnxt) {
        int ict = s / 25, tap = s - ict * 25;
        if (tap == 0) __syncthreads();
        if (s + 1 < 200) loadB(s + 1, bnxt);
        if (tap == 24 && ict < 7) stageA(ict + 1, abuf ^ 1);
        int dy = tap / 5, dx = tap - dy * 5;
        frag8 a[4];
#pragma unroll
        for (int i = 0; i < 4; i++)
            a[i] = *(const frag8*)&Asm[abuf][((wave * 4 + i + dy) * 20 + m16 + dx) * 32 + q * 8];
#pragma unroll
        for (int i = 0; i < 4; i++)
#pragma unroll
            for (int j = 0; j < 8; j++)
                acc[i][j] = __builtin_amdgcn_mfma_f32_16x16x32_bf16(a[i], bcur[j], acc[i][j], 0, 0, 0);
        if (tap == 24) abuf ^= 1;
    };
    for (int s = 0; s < 200; s += 2) { step(s, bA, bB); step(s + 1, bB, bA); }

#pragma unroll
    for (int j = 0; j < 8; j++) {
        int oc = oh * 128 + j * 16 + m16;
        float bj = bias[oc];
#pragma unroll
        for (int i = 0; i < 4; i++) {
            int r = wave * 4 + i;
            f32x4 v = acc[i][j];
            union { __half h[4]; double d; } u;
#pragma unroll
            for (int e = 0; e < 4; e++) {
                float t = v[e] + bj;
                u.h[e] = __float2half(t > 0.f ? t : 0.f);
            }
            *(double*)&pf[(size_t)oc * P2 + (by * 8 + r) * 256 + bx * 16 + q * 4] = u.d;
        }
    }
}

// ---------------------------------------------------------------- guided filter: streaming separable
__global__ __launch_bounds__(256) void gf_stream(const __half* __restrict__ p,
                                                 const float* __restrict__ guide,
                                                 const float* __restrict__ meanI,
                                                 const float* __restrict__ varI,
                                                 __hip_bfloat16* __restrict__ filt) {
    __shared__ float Prow[260], IProw[260], Arow[260], Brow[260];
    const int t = threadIdx.x;
    const int c = blockIdx.y;
    const int Y0 = blockIdx.x * 64;
    const __half* pc = p + (size_t)c * P2;
    if (t < 4) {
        int e = (t < 2) ? t : 256 + t;
        Prow[e] = 0.f; IProw[e] = 0.f; Arow[e] = 0.f; Brow[e] = 0.f;
    }
    int xlo = (t - 2 > 0) ? t - 2 : 0, xhi = (t + 2 < 255) ? t + 2 : 255;
    const float cxr = 1.0f / (float)(xhi - xlo + 1);
    float hp[5] = {0, 0, 0, 0, 0}, hip[5] = {0, 0, 0, 0, 0};
    float ha[5] = {0, 0, 0, 0, 0}, hb[5] = {0, 0, 0, 0, 0};
    float vp = 0.f, vip = 0.f, va = 0.f, vb = 0.f;
    __syncthreads();
    for (int s = 0; s < 72; s++) {
        int yL = Y0 - 4 + s;
        bool okL = ((unsigned)yL < 256u);
        if (okL) {
            float pv = __half2float(pc[yL * 256 + t]);
            Prow[t + 2] = pv;
            IProw[t + 2] = guide[yL * 256 + t] * pv;
        }
        __syncthreads();
        float hpn = 0.f, hipn = 0.f;
        if (okL) {
            hpn  = Prow[t] + Prow[t + 1] + Prow[t + 2] + Prow[t + 3] + Prow[t + 4];
            hipn = IProw[t] + IProw[t + 1] + IProw[t + 2] + IProw[t + 3] + IProw[t + 4];
        }
        vp += hpn - hp[0];  vip += hipn - hip[0];
        hp[0] = hp[1]; hp[1] = hp[2]; hp[2] = hp[3]; hp[3] = hp[4]; hp[4] = hpn;
        hip[0] = hip[1]; hip[1] = hip[2]; hip[2] = hip[3]; hip[3] = hip[4]; hip[4] = hipn;
        int yA = yL - 2;
        float aV = 0.f, bV = 0.f;
        if ((unsigned)yA < 256u && yA >= Y0 - 2) {
            int ylo = (yA - 2 > 0) ? yA - 2 : 0, yhi = (yA + 2 < 255) ? yA + 2 : 255;
            float inv1 = cxr / (float)(yhi - ylo + 1);
            float mI = meanI[yA * 256 + t], vI = varI[yA * 256 + t];
            float mp = vp * inv1, mip = vip * inv1;
            float cov = mip - mI * mp;
            aV = cov / (vI + 0.01f);
            bV = mp - aV * mI;
        }
        Arow[t + 2] = aV;
        Brow[t + 2] = bV;
        __syncthreads();
        float han = Arow[t] + Arow[t + 1] + Arow[t + 2] + Arow[t + 3] + Arow[t + 4];
        float hbn = Brow[t] + Brow[t + 1] + Brow[t + 2] + Brow[t + 3] + Brow[t + 4];
        va += han - ha[0];  vb += hbn - hb[0];
        ha[0] = ha[1]; ha[1] = ha[2]; ha[2] = ha[3]; ha[3] = ha[4]; ha[4] = han;
        hb[0] = hb[1]; hb[1] = hb[2]; hb[2] = hb[3]; hb[3] = hb[4]; hb[4] = hbn;
        int yo = yL - 4;
        if (yo >= Y0 && yo < Y0 + 64 && (unsigned)yo < 256u) {
            int ylo = (yo - 2 > 0) ? yo - 2 : 0, yhi = (yo + 2 < 255) ? yo + 2 : 255;
            float inv2 = cxr / (float)(yhi - ylo + 1);
            float I = guide[yo * 256 + t];
            filt[(size_t)c * P2 + yo * 256 + t] = __float2bfloat16((va * I + vb) * inv2);
        }
    }
}

// ---------------------------------------------------------------- transpose bf16 [c][p] -> chunk-planar
__global__ void transpose_cp(const __hip_bfloat16* __restrict__ filt,
                             __hip_bfloat16* __restrict__ filtp) {
    __shared__ __hip_bfloat16 T[8][1032];
    int tid = threadIdx.x;
    int p0 = blockIdx.x * 1024;
    int cg = blockIdx.y;
    for (int i = tid; i < 4096; i += 256) {
        int r = i >> 9, pl2 = (i & 511) * 2;
        unsigned v = *(const unsigned*)&filt[(size_t)(cg * 8 + r) * P2 + p0 + pl2];
        *(unsigned*)&T[r][pl2] = v;
    }
    __syncthreads();
    for (int pl = tid; pl < 1024; pl += 256) {
        union { __hip_bfloat16 h[8]; f32x4 v; } u;
#pragma unroll
        for (int j = 0; j < 8; j++) u.h[j] = T[j][pl];
        *(f32x4*)&filtp[((size_t)cg * P2 + p0 + pl) * 8] = u.v;
    }
}

// ---------------------------------------------------------------- sigmoid head finalize
__global__ void sigmoid_head(const float* __restrict__ haccum, const float* __restrict__ bm,
                             float* __restrict__ out) {
    int p = blockIdx.x * 256 + threadIdx.x;
    out[p] = 1.0f / (1.0f + expf(-(haccum[p] + bm[0])));
}

// ---------------------------------------------------------------- launch
extern "C" void kernel_launch(void* const* d_in, const int* in_sizes, int n_in,
                              void* d_out, int out_size, void* d_ws, size_t ws_size,
                              hipStream_t stream) {
    const float* fg   = (const float*)d_in[0];
    const float* bg   = (const float*)d_in[1];
    const float* mask = (const float*)d_in[2];
    const float* feat = (const float*)d_in[3];
    const float* w1   = (const float*)d_in[4];
    const float* b1   = (const float*)d_in[5];
    const float* w2   = (const float*)d_in[6];
    const float* b2   = (const float*)d_in[7];
    const float* w3   = (const float*)d_in[8];
    const float* b3   = (const float*)d_in[9];
    const float* wm   = (const float*)d_in[10];
    const float* bm   = (const float*)d_in[11];
    float* out = (float*)d_out;
    char* w8 = (char*)d_ws;

    __half* pbuf          = (__half*)w8;                         // 33,554,432 B (conv2 out fp16 [c][p])
    __hip_bfloat16* filtp = (__hip_bfloat16*)(w8 + 33554432);    // 33,554,432 B [32][P2][8]
    __hip_bfloat16* filt  = (__hip_bfloat16*)(w8 + 67108864);    // 33,554,432 B [c][p] (gf out)
    __hip_bfloat16* xlo   = (__hip_bfloat16*)(w8 + 67108864);    // 9,437,184 B — alias filt (dead before gf)
    __hip_bfloat16* zbuf  = (__hip_bfloat16*)(w8 + 76546048);    // 8,388,608 B — alias filt (dead before gf)
    __hip_bfloat16* y1p   = (__hip_bfloat16*)(w8 + 104857600);   // 34,611,200 B
    __hip_bfloat16* wpk2  = (__hip_bfloat16*)(w8 + 139468800);   // 3,276,800 B
    __hip_bfloat16* wpk1  = (__hip_bfloat16*)(w8 + 142745600);   // 147,456 B
    __hip_bfloat16* wpk3  = (__hip_bfloat16*)(w8 + 142893056);   // 131,072 B
    float* guide  = (float*)(w8 + 143024128);
    float* meanI  = guide + P2;
    float* varI   = meanI + P2;
    float* haccum = varI + P2;

    // 1. merged prep (lo-res x pack + guide/stats + border + haccum-zero + repacks)
    prep_mega<<<3621, 256, 0, stream>>>(mask, fg, bg, feat, w1, w2, w3,
                                        xlo, guide, meanI, varI, wpk1, wpk2, wpk3, y1p, haccum);
    // 2. conv1 at lo-res: z = W1@x_lo + b1 (no relu)
    gemm_z<<<dim3(128, 2), 256, 0, stream>>>(xlo, wpk1, b1, zbuf);
    // 3. upsample z 2x + relu -> y1p (bf16, padded NHWC)
    upsample_y1<<<8192, 256, 0, stream>>>(zbuf, y1p);
    // 4. conv2 (5x5 MFMA, R8 core) -> pbuf (fp16 [c][p])
    conv5x5_mfma<<<dim3(16, 32, 2), 128, 0, stream>>>(y1p, wpk2, b2, pbuf);
    // 5. guided filter -> filt (bf16 [c][p])
    gf_stream<<<dim3(4, 256), 256, 0, stream>>>(pbuf, guide, meanI, varI, filt);
    // 6. transpose -> filtp
    transpose_cp<<<dim3(64, 32), 256, 0, stream>>>(filt, filtp);
    // 7. conv3 (1x1 MFMA merged, fused head partials) -> out+P2 & haccum
    mfma_1x1<1><<<512, 256, 0, stream>>>(filtp, wpk3, b3, out + P2, 8, wm, haccum);
    // 8. sigmoid head -> out[0..P2)
    sigmoid_head<<<256, 256, 0, stream>>>(haccum, bm, out);
}